// Round 7
// baseline (88.469 us; speedup 1.0000x reference)
//
#include <hip/hip_runtime.h>

typedef _Float16 f16x8 __attribute__((ext_vector_type(8)));
typedef _Float16 f16x2 __attribute__((ext_vector_type(2)));
typedef float f32x2 __attribute__((ext_vector_type(2)));
typedef float f32x16 __attribute__((ext_vector_type(16)));

static __device__ __forceinline__ unsigned cvtpk_u(float a, float b) {
    unsigned r;
    asm("v_cvt_pkrtz_f16_f32 %0, %1, %2" : "=v"(r) : "v"(a), "v"(b));
    return r;
}

static __device__ __forceinline__ f16x8 mk_frag(unsigned a, unsigned b, unsigned c, unsigned d) {
    union { unsigned u[4]; f16x8 v; } x;
    x.u[0]=a; x.u[1]=b; x.u[2]=c; x.u[3]=d; return x.v;
}

union H2U { unsigned u; f16x2 h; };

// Packed rational tanh (2 values/op, all full-rate VALU, no trans):
// tanh x ~= x*(u^2/64 + (105/64)u + 945/64) / ((15/64)u^2 + (420/64)u + 945/64),
// u = x^2, input clamped to [-8,8], output clamped to [-1,1].
// All coefficients exactly representable in f16; den in [14.77, 1395].
// Division: packed int-magic (borrow-free for this den range) + 2 Newton steps.
static __device__ __forceinline__ unsigned tanh2pk(float a, float b) {
    H2U x; x.u = cvtpk_u(a, b);
    const f16x2 p8  = {(_Float16)8.0f,  (_Float16)8.0f};
    const f16x2 m8  = {(_Float16)-8.0f, (_Float16)-8.0f};
    f16x2 xv = __builtin_elementwise_min(__builtin_elementwise_max(x.h, m8), p8);
    f16x2 u = xv * xv;
    const _Float16 n2 = (_Float16)0.015625f;    // 1/64
    const _Float16 n1 = (_Float16)1.640625f;    // 105/64
    const _Float16 n0 = (_Float16)14.765625f;   // 945/64
    const _Float16 q2 = (_Float16)0.234375f;    // 15/64
    const _Float16 q1 = (_Float16)6.5625f;      // 420/64
    f16x2 num = (u * n2 + n1) * u + n0;
    f16x2 den = (u * q2 + q1) * u + n0;
    H2U db; db.h = den;
    H2U r0; r0.u = 0x778D778Du - db.u;          // f16 magic rcp seed (~5% err)
    const _Float16 two = (_Float16)2.0f;
    f16x2 r = r0.h * (two - den * r0.h);        // NR1
    r = r * (two - den * r);                    // NR2
    f16x2 t = xv * num * r;
    const f16x2 p1 = {(_Float16)1.0f,  (_Float16)1.0f};
    const f16x2 m1 = {(_Float16)-1.0f, (_Float16)-1.0f};
    t = __builtin_elementwise_min(__builtin_elementwise_max(t, m1), p1);
    H2U o; o.h = t; return o.u;
}

// f(e,g): L1 f16 MFMA (A=W1, B=[e,g]) -> pk-rational tanh -> L2 f16 MFMA
// (A=W2^T) -> pk-rational tanh -> f32 dot with W3 -> softplus.
static __device__ __forceinline__ float mlp_f(float e, float g,
        f16x8 A1, const f32x16& b1v,
        f16x8 A20, f16x8 A21, const f32x16& b2v,
        const f32x16& w3v, float b3v)
{
    // L1 B-operand: k0=e, k1=g, k2..15=0
    unsigned w0 = cvtpk_u(e, g);
    auto s0 = __builtin_amdgcn_permlane32_swap((int)w0, 0, false, false);
    f16x8 Bg1 = mk_frag((unsigned)s0[0], 0u, 0u, 0u);
    f16x8 Bg2 = mk_frag((unsigned)s0[1], 0u, 0u, 0u);
    f32x16 d1 = __builtin_amdgcn_mfma_f32_32x32x16_f16(A1, Bg1, b1v, 0, 0, 0);
    f32x16 d2 = __builtin_amdgcn_mfma_f32_32x32x16_f16(A1, Bg2, b1v, 0, 0, 0);

    // h1 = tanh(pre1), packed f16 pairs (rows 2m,2m+1)
    unsigned P[8], Q[8];
#pragma unroll
    for (int m = 0; m < 8; ++m) {
        P[m] = tanh2pk(d1[2*m], d1[2*m+1]);
        Q[m] = tanh2pk(d2[2*m], d2[2*m+1]);
    }

    // L2: pre2^T = W2^T @ h1^T + b2 (same permlane routing as verified R5)
    f32x16 a1, a2;
    {
        auto u02 = __builtin_amdgcn_permlane32_swap((int)P[0], (int)P[2], false, false);
        auto u13 = __builtin_amdgcn_permlane32_swap((int)P[1], (int)P[3], false, false);
        f16x8 Bq = mk_frag((unsigned)u02[0], (unsigned)u13[0], (unsigned)u02[1], (unsigned)u13[1]);
        a1 = __builtin_amdgcn_mfma_f32_32x32x16_f16(A20, Bq, b2v, 0, 0, 0);
        auto v02 = __builtin_amdgcn_permlane32_swap((int)P[4], (int)P[6], false, false);
        auto v13 = __builtin_amdgcn_permlane32_swap((int)P[5], (int)P[7], false, false);
        f16x8 Br = mk_frag((unsigned)v02[0], (unsigned)v13[0], (unsigned)v02[1], (unsigned)v13[1]);
        a1 = __builtin_amdgcn_mfma_f32_32x32x16_f16(A21, Br, a1, 0, 0, 0);
    }
    {
        auto u02 = __builtin_amdgcn_permlane32_swap((int)Q[0], (int)Q[2], false, false);
        auto u13 = __builtin_amdgcn_permlane32_swap((int)Q[1], (int)Q[3], false, false);
        f16x8 Bq = mk_frag((unsigned)u02[0], (unsigned)u13[0], (unsigned)u02[1], (unsigned)u13[1]);
        a2 = __builtin_amdgcn_mfma_f32_32x32x16_f16(A20, Bq, b2v, 0, 0, 0);
        auto v02 = __builtin_amdgcn_permlane32_swap((int)Q[4], (int)Q[6], false, false);
        auto v13 = __builtin_amdgcn_permlane32_swap((int)Q[5], (int)Q[7], false, false);
        f16x8 Br = mk_frag((unsigned)v02[0], (unsigned)v13[0], (unsigned)v02[1], (unsigned)v13[1]);
        a2 = __builtin_amdgcn_mfma_f32_32x32x16_f16(A21, Br, a2, 0, 0, 0);
    }

    // L3: o = b3 + sum w3[row] * tanh(pre2[row]); dot in f32
    f32x2 acc1 = {0.0f, 0.0f}, acc2 = {0.0f, 0.0f};
#pragma unroll
    for (int m = 0; m < 8; ++m) {
        H2U t1; t1.u = tanh2pk(a1[2*m], a1[2*m+1]);
        f32x2 f1 = __builtin_convertvector(t1.h, f32x2);
        f32x2 wp = {w3v[2*m], w3v[2*m+1]};
        acc1 = f1 * wp + acc1;
        H2U t2; t2.u = tanh2pk(a2[2*m], a2[2*m+1]);
        f32x2 f2 = __builtin_convertvector(t2.h, f32x2);
        acc2 = f2 * wp + acc2;
    }
    float pA = acc1[0] + acc1[1];
    float pB = acc2[0] + acc2[1];
    auto c = __builtin_amdgcn_permlane32_swap(__float_as_int(pA), __float_as_int(pB), false, false);
    float o = b3v + __int_as_float(c[0]) + __int_as_float(c[1]);
    return __logf(1.0f + __expf(o));   // softplus; |o| <~ 6
}

__global__ __launch_bounds__(256, 1) void gamma_rk4_mfma(
        const float4* __restrict__ inp, const float* __restrict__ gamma,
        const float* __restrict__ W1, const float* __restrict__ b1,
        const float* __restrict__ W2, const float* __restrict__ b2,
        const float* __restrict__ W3, const float* __restrict__ b3,
        float* __restrict__ out, int B)
{
    int idx  = blockIdx.x * 256 + threadIdx.x;
    int lane = threadIdx.x & 63;
    int hi   = lane >> 5;
    int arow = lane & 31;

    // L1 A-frag: lane holds A[row=l&31][k=8*(l>>5)+i]; k0=W1[0][j], k1=W1[1][j]
    f16x8 A1;
    {
        unsigned p10 = cvtpk_u(W1[arow], W1[32 + arow]);
        A1 = hi ? mk_frag(0u, 0u, 0u, 0u) : mk_frag(p10, 0u, 0u, 0u);
    }
    // L2 A = W2^T in f16 (two K=16 chunks): A[j][k] = W2[k][j]
    f16x8 A2[2];
#pragma unroll
    for (int s = 0; s < 2; ++s) {
        unsigned w[4];
#pragma unroll
        for (int m = 0; m < 4; ++m) {
            w[m] = cvtpk_u(W2[(16*s + 8*hi + 2*m    ) * 32 + arow],
                           W2[(16*s + 8*hi + 2*m + 1) * 32 + arow]);
        }
        A2[s] = mk_frag(w[0], w[1], w[2], w[3]);
    }
    // C/D row map: row = (r&3) + 8*(r>>2) + 4*hi
    f32x16 b1v, b2v, w3v;
#pragma unroll
    for (int r = 0; r < 16; ++r) {
        int row = (r & 3) + 8 * (r >> 2) + 4 * hi;
        b1v[r] = b1[row];
        b2v[r] = b2[row];
        w3v[r] = W3[row];
    }
    float b3v = b3[0];

    if (idx >= B) return;
    float4 v  = inp[idx];                 // eps_n, eps_half, eps_one, dt
    float g0  = gamma[idx];

    float k1 = v.w * mlp_f(v.x, g0, A1, b1v, A2[0], A2[1], b2v, w3v, b3v) * (v.x - g0);
    float g1 = fmaf(0.5f, k1, g0);
    float k2 = v.w * mlp_f(v.y, g1, A1, b1v, A2[0], A2[1], b2v, w3v, b3v) * (v.y - g1);
    float g2 = fmaf(0.5f, k2, g0);
    float k3 = v.w * mlp_f(v.y, g2, A1, b1v, A2[0], A2[1], b2v, w3v, b3v) * (v.y - g2);
    float g3 = g0 + k3;
    float k4 = v.w * mlp_f(v.z, g3, A1, b1v, A2[0], A2[1], b2v, w3v, b3v) * (v.z - g3);

    out[idx] = g0 + (k1 + 2.0f * (k2 + k3) + k4) * (1.0f / 6.0f);
}

extern "C" void kernel_launch(void* const* d_in, const int* in_sizes, int n_in,
                              void* d_out, int out_size, void* d_ws, size_t ws_size,
                              hipStream_t stream) {
    const float4* inp   = (const float4*)d_in[0];
    const float*  gamma = (const float*)d_in[1];
    const float*  W1    = (const float*)d_in[2];
    const float*  b1    = (const float*)d_in[3];
    const float*  W2    = (const float*)d_in[4];
    const float*  b2    = (const float*)d_in[5];
    const float*  W3    = (const float*)d_in[6];
    const float*  b3    = (const float*)d_in[7];
    float* out = (float*)d_out;

    int B = in_sizes[1];
    int block = 256;
    int grid = (B + block - 1) / block;
    gamma_rk4_mfma<<<grid, block, 0, stream>>>(inp, gamma, W1, b1, W2, b2,
                                               W3, b3, out, B);
}

// Round 8
// 86.972 us; speedup vs baseline: 1.0172x; 1.0172x over previous
//
#include <hip/hip_runtime.h>

typedef _Float16 f16x8 __attribute__((ext_vector_type(8)));
typedef float f32x16 __attribute__((ext_vector_type(16)));

static __device__ __forceinline__ unsigned cvtpk_u(float a, float b) {
    unsigned r;
    asm("v_cvt_pkrtz_f16_f32 %0, %1, %2" : "=v"(r) : "v"(a), "v"(b));
    return r;
}
static __device__ __forceinline__ f16x8 mk_frag(unsigned a, unsigned b, unsigned c, unsigned d) {
    union { unsigned u[4]; f16x8 v; } x;
    x.u[0]=a; x.u[1]=b; x.u[2]=c; x.u[3]=d; return x.v;
}

// Packed-f16 constants (u32 = two f16 halves), kept in VGPRs once.
struct TK {
    unsigned m8, p8, n2, n1, n0, q2, q1, two, p1, m1;
};

// Packed rational tanh, instruction-pinned. 2 values per call, 16 asm ops.
// tanh x ~= x*((u/64)u + 105/64)u+945/64) / (((15/64)u + 420/64)u + 945/64),
// u=x^2, x clamped to [-8,8], t clamped to [-1,1]. den in [14.77,1395] ->
// f16 int-magic 0x778D borrow-free; 2 Newton steps -> ~f16-accurate.
static __device__ __forceinline__ unsigned tanh2pk(float fa, float fb, const TK& k) {
    unsigned x0, xa, xb, u, n1_, nm, d1_, dn, r0, nd, s1, r1, s2, r2, pp, t0, t1, t2;
    asm("v_cvt_pkrtz_f16_f32 %0, %1, %2" : "=v"(x0) : "v"(fa), "v"(fb));
    asm("v_pk_max_f16 %0, %1, %2" : "=v"(xa) : "v"(x0), "v"(k.m8));
    asm("v_pk_min_f16 %0, %1, %2" : "=v"(xb) : "v"(xa), "v"(k.p8));
    asm("v_pk_mul_f16 %0, %1, %1" : "=v"(u)  : "v"(xb));
    asm("v_pk_fma_f16 %0, %1, %2, %3" : "=v"(n1_) : "v"(u), "v"(k.n2), "v"(k.n1));
    asm("v_pk_fma_f16 %0, %1, %2, %3" : "=v"(nm)  : "v"(n1_), "v"(u), "v"(k.n0));
    asm("v_pk_fma_f16 %0, %1, %2, %3" : "=v"(d1_) : "v"(u), "v"(k.q2), "v"(k.q1));
    asm("v_pk_fma_f16 %0, %1, %2, %3" : "=v"(dn)  : "v"(d1_), "v"(u), "v"(k.n0));
    asm("v_sub_u32 %0, %1, %2" : "=v"(r0) : "v"(0x778D778Du), "v"(dn));
    asm("v_xor_b32 %0, 0x80008000, %1" : "=v"(nd) : "v"(dn));
    asm("v_pk_fma_f16 %0, %1, %2, %3" : "=v"(s1) : "v"(nd), "v"(r0), "v"(k.two));
    asm("v_pk_mul_f16 %0, %1, %2" : "=v"(r1) : "v"(r0), "v"(s1));
    asm("v_pk_fma_f16 %0, %1, %2, %3" : "=v"(s2) : "v"(nd), "v"(r1), "v"(k.two));
    asm("v_pk_mul_f16 %0, %1, %2" : "=v"(r2) : "v"(r1), "v"(s2));
    asm("v_pk_mul_f16 %0, %1, %2" : "=v"(pp) : "v"(xb), "v"(nm));
    asm("v_pk_mul_f16 %0, %1, %2" : "=v"(t0) : "v"(pp), "v"(r2));
    asm("v_pk_min_f16 %0, %1, %2" : "=v"(t1) : "v"(t0), "v"(k.p1));
    asm("v_pk_max_f16 %0, %1, %2" : "=v"(t2) : "v"(t1), "v"(k.m1));
    return t2;
}

static __device__ __forceinline__ float mlp_f(float e, float g,
        f16x8 A1, const f32x16& b1v,
        f16x8 A20, f16x8 A21, const f32x16& b2v,
        const f32x16& w3v, float b3v, const TK& k)
{
    // L1 B-operand: k0=e, k1=g, rest 0
    unsigned w0 = cvtpk_u(e, g);
    auto s0 = __builtin_amdgcn_permlane32_swap((int)w0, 0, false, false);
    f16x8 Bg1 = mk_frag((unsigned)s0[0], 0u, 0u, 0u);
    f16x8 Bg2 = mk_frag((unsigned)s0[1], 0u, 0u, 0u);
    f32x16 d1 = __builtin_amdgcn_mfma_f32_32x32x16_f16(A1, Bg1, b1v, 0, 0, 0);
    f32x16 d2 = __builtin_amdgcn_mfma_f32_32x32x16_f16(A1, Bg2, b1v, 0, 0, 0);

    // h1 = tanh(pre1), packed f16 pairs
    unsigned P[8], Q[8];
#pragma unroll
    for (int m = 0; m < 8; ++m) {
        P[m] = tanh2pk(d1[2*m], d1[2*m+1], k);
        Q[m] = tanh2pk(d2[2*m], d2[2*m+1], k);
    }

    // L2: pre2^T = W2^T @ h1^T + b2 (permlane routing as verified R5/R7)
    f32x16 a1, a2;
    {
        auto u02 = __builtin_amdgcn_permlane32_swap((int)P[0], (int)P[2], false, false);
        auto u13 = __builtin_amdgcn_permlane32_swap((int)P[1], (int)P[3], false, false);
        f16x8 Bq = mk_frag((unsigned)u02[0], (unsigned)u13[0], (unsigned)u02[1], (unsigned)u13[1]);
        a1 = __builtin_amdgcn_mfma_f32_32x32x16_f16(A20, Bq, b2v, 0, 0, 0);
        auto v02 = __builtin_amdgcn_permlane32_swap((int)P[4], (int)P[6], false, false);
        auto v13 = __builtin_amdgcn_permlane32_swap((int)P[5], (int)P[7], false, false);
        f16x8 Br = mk_frag((unsigned)v02[0], (unsigned)v13[0], (unsigned)v02[1], (unsigned)v13[1]);
        a1 = __builtin_amdgcn_mfma_f32_32x32x16_f16(A21, Br, a1, 0, 0, 0);
    }
    {
        auto u02 = __builtin_amdgcn_permlane32_swap((int)Q[0], (int)Q[2], false, false);
        auto u13 = __builtin_amdgcn_permlane32_swap((int)Q[1], (int)Q[3], false, false);
        f16x8 Bq = mk_frag((unsigned)u02[0], (unsigned)u13[0], (unsigned)u02[1], (unsigned)u13[1]);
        a2 = __builtin_amdgcn_mfma_f32_32x32x16_f16(A20, Bq, b2v, 0, 0, 0);
        auto v02 = __builtin_amdgcn_permlane32_swap((int)Q[4], (int)Q[6], false, false);
        auto v13 = __builtin_amdgcn_permlane32_swap((int)Q[5], (int)Q[7], false, false);
        f16x8 Br = mk_frag((unsigned)v02[0], (unsigned)v13[0], (unsigned)v02[1], (unsigned)v13[1]);
        a2 = __builtin_amdgcn_mfma_f32_32x32x16_f16(A21, Br, a2, 0, 0, 0);
    }

    // L3: o = b3 + sum w3[row]*tanh(pre2[row]); dot in f32
    float pA = 0.0f, pB = 0.0f;
#pragma unroll
    for (int m = 0; m < 8; ++m) {
        union { unsigned u; _Float16 h[2]; } t1, t2;
        t1.u = tanh2pk(a1[2*m], a1[2*m+1], k);
        pA = fmaf(w3v[2*m], (float)t1.h[0], fmaf(w3v[2*m+1], (float)t1.h[1], pA));
        t2.u = tanh2pk(a2[2*m], a2[2*m+1], k);
        pB = fmaf(w3v[2*m], (float)t2.h[0], fmaf(w3v[2*m+1], (float)t2.h[1], pB));
    }
    auto c = __builtin_amdgcn_permlane32_swap(__float_as_int(pA), __float_as_int(pB), false, false);
    float o = b3v + __int_as_float(c[0]) + __int_as_float(c[1]);
    return __logf(1.0f + __expf(o));   // softplus; |o| <~ 6
}

__global__ __launch_bounds__(256, 1) void gamma_rk4_mfma(
        const float4* __restrict__ inp, const float* __restrict__ gamma,
        const float* __restrict__ W1, const float* __restrict__ b1,
        const float* __restrict__ W2, const float* __restrict__ b2,
        const float* __restrict__ W3, const float* __restrict__ b3,
        float* __restrict__ out, int B)
{
    int idx  = blockIdx.x * 256 + threadIdx.x;
    int lane = threadIdx.x & 63;
    int hi   = lane >> 5;
    int arow = lane & 31;

    TK k;
    k.m8 = 0xC800C800u;  // -8.0
    k.p8 = 0x48004800u;  //  8.0
    k.n2 = 0x24002400u;  //  1/64
    k.n1 = 0x3E903E90u;  //  105/64
    k.n0 = 0x4B624B62u;  //  945/64
    k.q2 = 0x33803380u;  //  15/64
    k.q1 = 0x46904690u;  //  420/64
    k.two= 0x40004000u;  //  2.0
    k.p1 = 0x3C003C00u;  //  1.0
    k.m1 = 0xBC00BC00u;  // -1.0

    // L1 A-frag: lane holds A[row=l&31][k=8*(l>>5)+i]; k0=W1[0][j], k1=W1[1][j]
    f16x8 A1;
    {
        unsigned p10 = cvtpk_u(W1[arow], W1[32 + arow]);
        A1 = hi ? mk_frag(0u, 0u, 0u, 0u) : mk_frag(p10, 0u, 0u, 0u);
    }
    // L2 A = W2^T in f16 (two K=16 chunks): A[j][k] = W2[k][j]
    f16x8 A2[2];
#pragma unroll
    for (int s = 0; s < 2; ++s) {
        unsigned w[4];
#pragma unroll
        for (int m = 0; m < 4; ++m) {
            w[m] = cvtpk_u(W2[(16*s + 8*hi + 2*m    ) * 32 + arow],
                           W2[(16*s + 8*hi + 2*m + 1) * 32 + arow]);
        }
        A2[s] = mk_frag(w[0], w[1], w[2], w[3]);
    }
    // C/D row map: row = (r&3) + 8*(r>>2) + 4*hi
    f32x16 b1v, b2v, w3v;
#pragma unroll
    for (int r = 0; r < 16; ++r) {
        int row = (r & 3) + 8 * (r >> 2) + 4 * hi;
        b1v[r] = b1[row];
        b2v[r] = b2[row];
        w3v[r] = W3[row];
    }
    float b3v = b3[0];

    if (idx >= B) return;
    float4 v  = inp[idx];                 // eps_n, eps_half, eps_one, dt
    float g0  = gamma[idx];

    float k1 = v.w * mlp_f(v.x, g0, A1, b1v, A2[0], A2[1], b2v, w3v, b3v, k) * (v.x - g0);
    float g1 = fmaf(0.5f, k1, g0);
    float k2 = v.w * mlp_f(v.y, g1, A1, b1v, A2[0], A2[1], b2v, w3v, b3v, k) * (v.y - g1);
    float g2 = fmaf(0.5f, k2, g0);
    float k3 = v.w * mlp_f(v.y, g2, A1, b1v, A2[0], A2[1], b2v, w3v, b3v, k) * (v.y - g2);
    float g3 = g0 + k3;
    float k4 = v.w * mlp_f(v.z, g3, A1, b1v, A2[0], A2[1], b2v, w3v, b3v, k) * (v.z - g3);

    out[idx] = g0 + (k1 + 2.0f * (k2 + k3) + k4) * (1.0f / 6.0f);
}

extern "C" void kernel_launch(void* const* d_in, const int* in_sizes, int n_in,
                              void* d_out, int out_size, void* d_ws, size_t ws_size,
                              hipStream_t stream) {
    const float4* inp   = (const float4*)d_in[0];
    const float*  gamma = (const float*)d_in[1];
    const float*  W1    = (const float*)d_in[2];
    const float*  b1    = (const float*)d_in[3];
    const float*  W2    = (const float*)d_in[4];
    const float*  b2    = (const float*)d_in[5];
    const float*  W3    = (const float*)d_in[6];
    const float*  b3    = (const float*)d_in[7];
    float* out = (float*)d_out;

    int B = in_sizes[1];
    int block = 256;
    int grid = (B + block - 1) / block;
    gamma_rk4_mfma<<<grid, block, 0, stream>>>(inp, gamma, W1, b1, W2, b2,
                                               W3, b3, out, B);
}